// Round 7
// baseline (392.479 us; speedup 1.0000x reference)
//
#include <hip/hip_runtime.h>

#define NSRC 100000
#define NTGT 50000
#define NE   600000
#define CH   128
#define NREL 7
#define NTYP 4
#define NP   (NREL * NTGT)          // 350000 (rel,dst) pairs
#define NB   ((NP + 1023) / 1024)   // scan blocks (342)
#define AGGB (NP / 16)              // 21875 blocks, 16 pairs each (exact)
#define GEMB 1563                   // ceil(3125 tiles * 2 ct-halves / 4 waves)

typedef __attribute__((ext_vector_type(4))) float f32x4;
typedef __attribute__((ext_vector_type(8))) short bf16x8;
typedef unsigned int uint;
typedef unsigned short ushort;

static constexpr long long NXB4 = (long long)NSRC * CH / 4;
static constexpr long long NXT4 = (long long)NTGT * CH / 4;
static constexpr long long NWR4 = (long long)NREL * CH * CH / 4;
static constexpr long long NWT4 = (long long)NTYP * CH * CH / 4;
static constexpr int CONVB  = (int)((NXB4 + NXT4 + NWR4 + NWT4 + 255) / 256);
static constexpr int COUNTB = (NE + 255) / 256;

// ---- workspace layout ----
static constexpr size_t A256(size_t x) { return (x + 255) & ~(size_t)255; }
static constexpr size_t CNT_O   = 0;                                   // int[NP] (memset 0)
static constexpr size_t BSE_O   = A256(CNT_O + (size_t)NP * 4);        // int[NB]
static constexpr size_t EOFF_O  = A256(BSE_O + (size_t)NB * 4);        // int[NP+1]
static constexpr size_t CUR_O   = A256(EOFF_O + (size_t)(NP + 1) * 4); // int[NP]
static constexpr size_t SEDGE_O = A256(CUR_O + (size_t)NP * 4);        // int[NE]
static constexpr size_t WB_O    = A256(SEDGE_O + (size_t)NE * 4);      // bf16[11*CH*CH]
static constexpr size_t XB_O    = A256(WB_O + (size_t)(NREL + NTYP) * CH * CH * 2);
static constexpr size_t XTB_O   = A256(XB_O + (size_t)NSRC * CH * 2);  // bf16[NTGT*CH]
static constexpr size_t MEAN_O  = A256(XTB_O + (size_t)NTGT * CH * 2); // bf16[NP*CH]

#define GLOAD_LDS(gp, lp) __builtin_amdgcn_global_load_lds( \
    (const __attribute__((address_space(1))) void*)(gp), \
    (__attribute__((address_space(3))) void*)(lp), 16, 0, 0)
#define WAITVM0()   asm volatile("s_waitcnt vmcnt(0)" ::: "memory")
#define WAITLGKM0() asm volatile("s_waitcnt lgkmcnt(0)" ::: "memory")
#define SB0()       __builtin_amdgcn_sched_barrier(0)

__device__ __forceinline__ uint bfpack(float a, float b) {
  uint ua = __float_as_uint(a); ua = (ua + 0x7fff + ((ua >> 16) & 1)) >> 16;
  uint ub = __float_as_uint(b); ub = (ub + 0x7fff + ((ub >> 16) & 1)) >> 16;
  return ua | (ub << 16);
}
__device__ __forceinline__ ushort f2b(float x) {
  uint u = __float_as_uint(x);
  return (ushort)((u + 0x7fff + ((u >> 16) & 1)) >> 16);
}
__device__ __forceinline__ float bl(uint u) { return __uint_as_float(u << 16); }
__device__ __forceinline__ float bh(uint u) { return __uint_as_float(u & 0xffff0000u); }

// ---- fused: fp32->bf16 conversion (xsrc + xt + weights) + (rel,dst) counting ----
__global__ __launch_bounds__(256) void k_pre(
    const float* __restrict__ xsrc, const float* __restrict__ xt,
    const float* __restrict__ relw, const float* __restrict__ rootw,
    ushort* __restrict__ xb, ushort* __restrict__ xtb, ushort* __restrict__ wb,
    const int* __restrict__ edst, const int* __restrict__ etyp,
    int* __restrict__ cnt) {
  int bx = blockIdx.x;
  if (bx < CONVB) {
    long long i4 = (long long)bx * 256 + threadIdx.x;
    const float* src; ushort* dst; long long off;
    if (i4 < NXB4) { src = xsrc; dst = xb; off = i4; }
    else if (i4 < NXB4 + NXT4) { src = xt; dst = xtb; off = i4 - NXB4; }
    else if (i4 < NXB4 + NXT4 + NWR4) { src = relw; dst = wb; off = i4 - NXB4 - NXT4; }
    else if (i4 < NXB4 + NXT4 + NWR4 + NWT4) {
      src = rootw; dst = wb + (size_t)NREL * CH * CH; off = i4 - NXB4 - NXT4 - NWR4;
    } else return;
    float4 v = *(const float4*)(src + off * 4);
    uint lo = (uint)f2b(v.x) | ((uint)f2b(v.y) << 16);
    uint hi = (uint)f2b(v.z) | ((uint)f2b(v.w) << 16);
    uint2 o = make_uint2(lo, hi);
    *(uint2*)(dst + off * 4) = o;
    return;
  }
  bx -= CONVB;
  int i = bx * 256 + threadIdx.x;
  if (i < NE) atomicAdd(&cnt[etyp[i] * NTGT + edst[i]], 1);
}

__global__ __launch_bounds__(256) void k_s1(const int* __restrict__ cnt,
                                            int* __restrict__ bsE) {
  __shared__ int sE[256];
  int t = threadIdx.x, p0 = blockIdx.x * 1024 + t * 4;
  int e = 0;
#pragma unroll
  for (int j = 0; j < 4; ++j) {
    int p = p0 + j;
    if (p < NP) e += cnt[p];
  }
  sE[t] = e; __syncthreads();
  for (int s = 128; s > 0; s >>= 1) {
    if (t < s) sE[t] += sE[t + s];
    __syncthreads();
  }
  if (t == 0) bsE[blockIdx.x] = sE[0];
}

// fused s2+s3: each block re-scans the 342 block sums, then scans its own chunk
__global__ __launch_bounds__(512) void k_s23(const int* __restrict__ cnt,
                                             const int* __restrict__ bsE,
                                             int* __restrict__ eoff,
                                             int* __restrict__ cur) {
  __shared__ int sE[512];
  __shared__ int sBase;
  int t = threadIdx.x;
  int e = (t < NB) ? bsE[t] : 0;
  sE[t] = e; __syncthreads();
  for (int s = 1; s < 512; s <<= 1) {
    int a = 0; if (t >= s) a = sE[t - s];
    __syncthreads();
    sE[t] += a;
    __syncthreads();
  }
  if (t == blockIdx.x) sBase = sE[t] - e;   // exclusive prefix for this block
  __syncthreads();
  int base0 = sBase;
  int p0 = blockIdx.x * 1024 + t * 2;
  int c0 = (p0 < NP) ? cnt[p0] : 0;
  int c1 = (p0 + 1 < NP) ? cnt[p0 + 1] : 0;
  int e2 = c0 + c1;
  sE[t] = e2; __syncthreads();
  for (int s = 1; s < 512; s <<= 1) {
    int a = 0; if (t >= s) a = sE[t - s];
    __syncthreads();
    sE[t] += a;
    __syncthreads();
  }
  int baseE = base0 + sE[t] - e2;
  if (p0 < NP)     { eoff[p0] = baseE;          cur[p0] = baseE; }
  if (p0 + 1 < NP) { eoff[p0 + 1] = baseE + c0; cur[p0 + 1] = baseE + c0; }
  if (p0 + 1 == NP - 1) eoff[NP] = baseE + c0 + c1;   // sentinel = NE
}

// ---- edge sort: bucket scatter of src indices into (rel,dst)-sorted order ----
__global__ __launch_bounds__(256) void k_esort(
    const int* __restrict__ esrc, const int* __restrict__ edst,
    const int* __restrict__ etyp, int* __restrict__ cur,
    int* __restrict__ sedge) {
  int i = blockIdx.x * 256 + threadIdx.x;
  if (i < NE) {
    int p = etyp[i] * NTGT + edst[i];
    int pos = atomicAdd(&cur[p], 1);
    sedge[pos] = esrc[i];
  }
}

// ---- pair-parallel segmented mean: one (rel,dst) pair per 16-lane group ----
// 21875 blocks (85 waves/CU of work): TLP hides all gather latency.
// Edges contiguous in sedge; indices lane-parallel -> register shfl broadcast;
// row gathers are independent coalesced 256B reads from L3-resident xb.
__global__ __launch_bounds__(256) void k_agg(
    const ushort* __restrict__ xb, const int* __restrict__ sedge,
    const int* __restrict__ eoff, ushort* __restrict__ mean) {
  int tid = threadIdx.x;
  int g = tid >> 4, l16 = tid & 15;
  int p = blockIdx.x * 16 + g;            // NP = 16 * AGGB exactly
  int lo = eoff[p], hi = eoff[p + 1];
  int cnt = hi - lo;
  float acc[8];
#pragma unroll
  for (int c = 0; c < 8; ++c) acc[c] = 0.f;
  int base = lo;
  while (base < hi) {
    int nb = hi - base; if (nb > 16) nb = 16;
    int sv = (l16 < nb) ? sedge[base + l16] : 0;   // lane-parallel index load
    for (int j = 0; j < nb; ++j) {
      int s = __shfl(sv, (g & 3) * 16 + j);        // register broadcast
      uint4 v = *(const uint4*)(xb + (size_t)s * CH + (l16 << 3));
      acc[0] += bl(v.x); acc[1] += bh(v.x);
      acc[2] += bl(v.y); acc[3] += bh(v.y);
      acc[4] += bl(v.z); acc[5] += bh(v.z);
      acc[6] += bl(v.w); acc[7] += bh(v.w);
    }
    base += 16;
  }
  float inv = (cnt > 0) ? __builtin_amdgcn_rcpf((float)cnt) : 0.f;
  uint4 o;
  o.x = bfpack(acc[0] * inv, acc[1] * inv);
  o.y = bfpack(acc[2] * inv, acc[3] * inv);
  o.z = bfpack(acc[4] * inv, acc[5] * inv);
  o.w = bfpack(acc[6] * inv, acc[7] * inv);
  *(uint4*)(mean + (size_t)p * CH + (l16 << 3)) = o;
}

// ---- dense GEMM: out = [mean_0..mean_6 | type-masked xtb] * W^T + bias ----
// Wave-unit = 16 dst rows x 64 out-ch (ct-half). 6250 waves = 24/CU of work.
// A-tiles contiguous -> global_load_lds with inverse-swizzled source (linear
// LDS dest), conflict-free swizzled ds_read_b128 A-fragments. Weights direct
// from L2-hot global. Root = 4 register-masked phases from one xtb tile.
__global__ __launch_bounds__(256) void k_gemm(
    const ushort* __restrict__ mean, const ushort* __restrict__ xtb,
    const ushort* __restrict__ wb, const int* __restrict__ ntyp,
    const float* __restrict__ rootb, float* __restrict__ out) {
  __shared__ ushort As[4 * 2048];         // 16 KB: 4 KB strip per wave
  int wv = threadIdx.x >> 6, ln = threadIdx.x & 63;
  ushort* strip = As + wv * 2048;
  int m = ln & 15, quad = ln >> 4;
  int w = blockIdx.x * 4 + wv;            // global wave id (< 6252)
  int tile = w >> 1, half = w & 1;        // 16-dst tile, ct-half
  int dstbase = tile * 16;
  if (dstbase >= NTGT) return;            // no block-wide syncs below
  int ct0 = half * 4;

  f32x4 acc[4];
#pragma unroll
  for (int ct = 0; ct < 4; ++ct) acc[ct] = (f32x4){0.f, 0.f, 0.f, 0.f};

  // ---- 7 mean phases ----
  for (int ph = 0; ph < NREL; ++ph) {
    const ushort* gb = mean + ((size_t)ph * NTGT + dstbase) * CH;
    WAITLGKM0(); SB0();                   // prior A-frag ds_reads retired (WAR)
#pragma unroll
    for (int t4 = 0; t4 < 4; ++t4) {
      int i = t4 * 4 + quad;              // row 0..15
      const ushort* gp = gb + (size_t)i * CH + ((m ^ i) << 3);  // inv-swizzled src
      GLOAD_LDS(gp, strip + t4 * 512);
    }
    WAITVM0(); SB0();                     // staged tile landed
    bf16x8 aF[4];
#pragma unroll
    for (int ks = 0; ks < 4; ++ks) {
      int c = ks * 4 + quad;
      aF[ks] = *(const bf16x8*)&strip[(m * 16 + (c ^ m)) << 3];
    }
    const ushort* W = wb + (size_t)ph * CH * CH;
#pragma unroll
    for (int ct = 0; ct < 4; ++ct) {
      int n = (ct0 + ct) * 16 + m;
#pragma unroll
      for (int ks = 0; ks < 4; ++ks) {
        bf16x8 bF = *(const bf16x8*)(W + (size_t)n * CH + ks * 32 + quad * 8);
        acc[ct] = __builtin_amdgcn_mfma_f32_16x16x32_bf16(aF[ks], bF, acc[ct], 0, 0, 0);
      }
    }
  }

  // ---- root: stage xtb tile once, 4 register-masked phases ----
  WAITLGKM0(); SB0();
#pragma unroll
  for (int t4 = 0; t4 < 4; ++t4) {
    int i = t4 * 4 + quad;
    const ushort* gp = xtb + (size_t)(dstbase + i) * CH + ((m ^ i) << 3);
    GLOAD_LDS(gp, strip + t4 * 512);
  }
  WAITVM0(); SB0();
  int myt = ntyp[dstbase + m];            // A-fragment row type (per lane)
  union { uint u[4]; bf16x8 v; } aT[4];
#pragma unroll
  for (int ks = 0; ks < 4; ++ks) {
    int c = ks * 4 + quad;
    aT[ks].v = *(const bf16x8*)&strip[(m * 16 + (c ^ m)) << 3];
  }
#pragma unroll
  for (int ty = 0; ty < NTYP; ++ty) {
    union { uint u[4]; bf16x8 v; } aM[4];
#pragma unroll
    for (int ks = 0; ks < 4; ++ks)
#pragma unroll
      for (int k2 = 0; k2 < 4; ++k2)
        aM[ks].u[k2] = (myt == ty) ? aT[ks].u[k2] : 0u;
    const ushort* W = wb + (size_t)(NREL + ty) * CH * CH;
#pragma unroll
    for (int ct = 0; ct < 4; ++ct) {
      int n = (ct0 + ct) * 16 + m;
#pragma unroll
      for (int ks = 0; ks < 4; ++ks) {
        bf16x8 bF = *(const bf16x8*)(W + (size_t)n * CH + ks * 32 + quad * 8);
        acc[ct] = __builtin_amdgcn_mfma_f32_16x16x32_bf16(aM[ks].v, bF, acc[ct], 0, 0, 0);
      }
    }
  }

  // ---- epilogue: add bias, plain coalesced store (64 cols per wave) ----
#pragma unroll
  for (int reg = 0; reg < 4; ++reg) {
    int row = quad * 4 + reg;
    int dst = dstbase + row;
    int tt = ntyp[dst];
    const float* rb = rootb + (size_t)tt * CH;
#pragma unroll
    for (int ct = 0; ct < 4; ++ct) {
      int col = (ct0 + ct) * 16 + m;
      out[(size_t)dst * CH + col] = acc[ct][reg] + rb[col];
    }
  }
}

extern "C" void kernel_launch(void* const* d_in, const int* in_sizes, int n_in,
                              void* d_out, int out_size, void* d_ws, size_t ws_size,
                              hipStream_t stream) {
  (void)in_sizes; (void)n_in; (void)out_size; (void)ws_size;
  const float* xsrc  = (const float*)d_in[0];
  const float* xt    = (const float*)d_in[1];
  const float* relw  = (const float*)d_in[2];
  const float* rootw = (const float*)d_in[3];
  const float* rootb = (const float*)d_in[4];
  const int* esrc = (const int*)d_in[5];
  const int* edst = (const int*)d_in[6];
  const int* etyp = (const int*)d_in[7];
  const int* ntyp = (const int*)d_in[8];
  float* out = (float*)d_out;

  char* ws = (char*)d_ws;
  int*   cnt    = (int*)(ws + CNT_O);
  int*   bsE    = (int*)(ws + BSE_O);
  int*   eoff   = (int*)(ws + EOFF_O);
  int*   cur    = (int*)(ws + CUR_O);
  int*   sedge  = (int*)(ws + SEDGE_O);
  ushort* wb    = (ushort*)(ws + WB_O);
  ushort* xb    = (ushort*)(ws + XB_O);
  ushort* xtb   = (ushort*)(ws + XTB_O);
  ushort* mean  = (ushort*)(ws + MEAN_O);

  hipMemsetAsync(cnt, 0, (size_t)NP * 4, stream);
  k_pre<<<dim3(CONVB + COUNTB), dim3(256), 0, stream>>>(
      xsrc, xt, relw, rootw, xb, xtb, wb, edst, etyp, cnt);
  k_s1<<<dim3(NB), dim3(256), 0, stream>>>(cnt, bsE);
  k_s23<<<dim3(NB), dim3(512), 0, stream>>>(cnt, bsE, eoff, cur);
  k_esort<<<dim3(COUNTB), dim3(256), 0, stream>>>(esrc, edst, etyp, cur, sedge);
  k_agg<<<dim3(AGGB), dim3(256), 0, stream>>>(xb, sedge, eoff, mean);
  k_gemm<<<dim3(GEMB), dim3(256), 0, stream>>>(
      mean, xtb, wb, ntyp, rootb, out);
}

// Round 8
// 391.239 us; speedup vs baseline: 1.0032x; 1.0032x over previous
//
#include <hip/hip_runtime.h>

#define NSRC 100000
#define NTGT 50000
#define NE   600000
#define CH   128
#define NREL 7
#define NTYP 4
#define NP   (NREL * NTGT)          // 350000 (rel,dst) pairs
#define NB   ((NP + 1023) / 1024)   // scan blocks (342)
#define AGGB (NP / 16)              // 21875 blocks, 16 pairs each (exact)
#define GEMB 1563                   // ceil(3125 tiles * 2 ct-halves / 4 waves)

typedef __attribute__((ext_vector_type(4))) float f32x4;
typedef __attribute__((ext_vector_type(8))) short bf16x8;
typedef unsigned int uint;
typedef unsigned short ushort;

static constexpr long long NXB4 = (long long)NSRC * CH / 4;
static constexpr long long NXT4 = (long long)NTGT * CH / 4;
static constexpr long long NWR4 = (long long)NREL * CH * CH / 4;
static constexpr long long NWT4 = (long long)NTYP * CH * CH / 4;
static constexpr int CONVB  = (int)((NXB4 + NXT4 + NWR4 + NWT4 + 255) / 256);
static constexpr int COUNTB = (NE + 255) / 256;

// ---- workspace layout ----
static constexpr size_t A256(size_t x) { return (x + 255) & ~(size_t)255; }
static constexpr size_t CNT_O   = 0;                                   // int[NP] (memset 0)
static constexpr size_t BSE_O   = A256(CNT_O + (size_t)NP * 4);        // int[NB]
static constexpr size_t EOFF_O  = A256(BSE_O + (size_t)NB * 4);        // int[NP+1]
static constexpr size_t CUR_O   = A256(EOFF_O + (size_t)(NP + 1) * 4); // int[NP]
static constexpr size_t SEDGE_O = A256(CUR_O + (size_t)NP * 4);        // int[NE]
static constexpr size_t WB_O    = A256(SEDGE_O + (size_t)NE * 4);      // bf16[11*CH*CH]
static constexpr size_t XB_O    = A256(WB_O + (size_t)(NREL + NTYP) * CH * CH * 2);
static constexpr size_t XTB_O   = A256(XB_O + (size_t)NSRC * CH * 2);  // bf16[NTGT*CH]
static constexpr size_t MEAN_O  = A256(XTB_O + (size_t)NTGT * CH * 2); // bf16[NP*CH]

__device__ __forceinline__ uint bfpack(float a, float b) {
  uint ua = __float_as_uint(a); ua = (ua + 0x7fff + ((ua >> 16) & 1)) >> 16;
  uint ub = __float_as_uint(b); ub = (ub + 0x7fff + ((ub >> 16) & 1)) >> 16;
  return ua | (ub << 16);
}
__device__ __forceinline__ ushort f2b(float x) {
  uint u = __float_as_uint(x);
  return (ushort)((u + 0x7fff + ((u >> 16) & 1)) >> 16);
}
__device__ __forceinline__ float bl(uint u) { return __uint_as_float(u << 16); }
__device__ __forceinline__ float bh(uint u) { return __uint_as_float(u & 0xffff0000u); }

__device__ __forceinline__ void add8(float* a, uint4 u) {
  a[0] += bl(u.x); a[1] += bh(u.x);
  a[2] += bl(u.y); a[3] += bh(u.y);
  a[4] += bl(u.z); a[5] += bh(u.z);
  a[6] += bl(u.w); a[7] += bh(u.w);
}

// ---- fused: fp32->bf16 conversion (xsrc + xt + weights) + (rel,dst) counting ----
__global__ __launch_bounds__(256) void k_pre(
    const float* __restrict__ xsrc, const float* __restrict__ xt,
    const float* __restrict__ relw, const float* __restrict__ rootw,
    ushort* __restrict__ xb, ushort* __restrict__ xtb, ushort* __restrict__ wb,
    const int* __restrict__ edst, const int* __restrict__ etyp,
    int* __restrict__ cnt) {
  int bx = blockIdx.x;
  if (bx < CONVB) {
    long long i4 = (long long)bx * 256 + threadIdx.x;
    const float* src; ushort* dst; long long off;
    if (i4 < NXB4) { src = xsrc; dst = xb; off = i4; }
    else if (i4 < NXB4 + NXT4) { src = xt; dst = xtb; off = i4 - NXB4; }
    else if (i4 < NXB4 + NXT4 + NWR4) { src = relw; dst = wb; off = i4 - NXB4 - NXT4; }
    else if (i4 < NXB4 + NXT4 + NWR4 + NWT4) {
      src = rootw; dst = wb + (size_t)NREL * CH * CH; off = i4 - NXB4 - NXT4 - NWR4;
    } else return;
    float4 v = *(const float4*)(src + off * 4);
    uint lo = (uint)f2b(v.x) | ((uint)f2b(v.y) << 16);
    uint hi = (uint)f2b(v.z) | ((uint)f2b(v.w) << 16);
    uint2 o = make_uint2(lo, hi);
    *(uint2*)(dst + off * 4) = o;
    return;
  }
  bx -= CONVB;
  int i = bx * 256 + threadIdx.x;
  if (i < NE) atomicAdd(&cnt[etyp[i] * NTGT + edst[i]], 1);
}

__global__ __launch_bounds__(256) void k_s1(const int* __restrict__ cnt,
                                            int* __restrict__ bsE) {
  __shared__ int sE[256];
  int t = threadIdx.x, p0 = blockIdx.x * 1024 + t * 4;
  int e = 0;
#pragma unroll
  for (int j = 0; j < 4; ++j) {
    int p = p0 + j;
    if (p < NP) e += cnt[p];
  }
  sE[t] = e; __syncthreads();
  for (int s = 128; s > 0; s >>= 1) {
    if (t < s) sE[t] += sE[t + s];
    __syncthreads();
  }
  if (t == 0) bsE[blockIdx.x] = sE[0];
}

// fused s2+s3: each block re-scans the 342 block sums, then scans its own chunk
__global__ __launch_bounds__(512) void k_s23(const int* __restrict__ cnt,
                                             const int* __restrict__ bsE,
                                             int* __restrict__ eoff,
                                             int* __restrict__ cur) {
  __shared__ int sE[512];
  __shared__ int sBase;
  int t = threadIdx.x;
  int e = (t < NB) ? bsE[t] : 0;
  sE[t] = e; __syncthreads();
  for (int s = 1; s < 512; s <<= 1) {
    int a = 0; if (t >= s) a = sE[t - s];
    __syncthreads();
    sE[t] += a;
    __syncthreads();
  }
  if (t == blockIdx.x) sBase = sE[t] - e;   // exclusive prefix for this block
  __syncthreads();
  int base0 = sBase;
  int p0 = blockIdx.x * 1024 + t * 2;
  int c0 = (p0 < NP) ? cnt[p0] : 0;
  int c1 = (p0 + 1 < NP) ? cnt[p0 + 1] : 0;
  int e2 = c0 + c1;
  sE[t] = e2; __syncthreads();
  for (int s = 1; s < 512; s <<= 1) {
    int a = 0; if (t >= s) a = sE[t - s];
    __syncthreads();
    sE[t] += a;
    __syncthreads();
  }
  int baseE = base0 + sE[t] - e2;
  if (p0 < NP)     { eoff[p0] = baseE;          cur[p0] = baseE; }
  if (p0 + 1 < NP) { eoff[p0 + 1] = baseE + c0; cur[p0 + 1] = baseE + c0; }
  if (p0 + 1 == NP - 1) eoff[NP] = baseE + c0 + c1;   // sentinel = NE
}

// ---- edge sort: bucket scatter of src indices into (rel,dst)-sorted order ----
__global__ __launch_bounds__(256) void k_esort(
    const int* __restrict__ esrc, const int* __restrict__ edst,
    const int* __restrict__ etyp, int* __restrict__ cur,
    int* __restrict__ sedge) {
  int i = blockIdx.x * 256 + threadIdx.x;
  if (i < NE) {
    int p = etyp[i] * NTGT + edst[i];
    int pos = atomicAdd(&cur[p], 1);
    sedge[pos] = esrc[i];
  }
}

// ---- pair-parallel segmented mean: one (rel,dst) pair per 16-lane group ----
// 21875 blocks (85 waves/CU of work). Inner loop is a STATIC 8-wide unroll with
// exec-masked loads: up to 8 independent 256B row gathers in flight per group
// (avg pair has 1.7 edges -> one chunk covers >99.99% of pairs).
__global__ __launch_bounds__(256) void k_agg(
    const ushort* __restrict__ xb, const int* __restrict__ sedge,
    const int* __restrict__ eoff, ushort* __restrict__ mean) {
  int tid = threadIdx.x;
  int g = tid >> 4, l16 = tid & 15;
  int p = blockIdx.x * 16 + g;            // NP = 16 * AGGB exactly
  int lo = eoff[p], hi = eoff[p + 1];
  int cnt = hi - lo;
  float acc[8];
#pragma unroll
  for (int c = 0; c < 8; ++c) acc[c] = 0.f;
  for (int base = lo; base < hi; base += 8) {
    int sv = (l16 < 8 && base + l16 < hi) ? sedge[base + l16] : 0;
#pragma unroll
    for (int j = 0; j < 8; ++j) {
      int s = __shfl(sv, (g & 3) * 16 + j);   // register broadcast
      if (base + j < hi) {                    // uniform per 16-lane group
        uint4 v = *(const uint4*)(xb + (size_t)s * CH + (l16 << 3));
        add8(acc, v);
      }
    }
  }
  float inv = (cnt > 0) ? __builtin_amdgcn_rcpf((float)cnt) : 0.f;
  uint4 o;
  o.x = bfpack(acc[0] * inv, acc[1] * inv);
  o.y = bfpack(acc[2] * inv, acc[3] * inv);
  o.z = bfpack(acc[4] * inv, acc[5] * inv);
  o.w = bfpack(acc[6] * inv, acc[7] * inv);
  *(uint4*)(mean + (size_t)p * CH + (l16 << 3)) = o;
}

// ---- dense GEMM: out = [mean_0..mean_6 | type-masked xtb] * W^T + bias ----
// LDS-FREE, FENCE-FREE. A-fragments load directly global->VGPR (fragment layout
// needs no swizzle without an LDS round-trip); 2-phase software pipeline, fully
// unrolled; B-fragments from L1/L2-hot weights. Compiler inserts counted
// per-use waits -> no full vmcnt(0) drains, waves stay short, TLP overlaps.
__global__ __launch_bounds__(256) void k_gemm(
    const ushort* __restrict__ mean, const ushort* __restrict__ xtb,
    const ushort* __restrict__ wb, const int* __restrict__ ntyp,
    const float* __restrict__ rootb, float* __restrict__ out) {
  int wv = threadIdx.x >> 6, ln = threadIdx.x & 63;
  int m = ln & 15, quad = ln >> 4;
  int w = blockIdx.x * 4 + wv;            // global wave id (< 6252)
  int tile = w >> 1, half = w & 1;        // 16-dst tile, ct-half
  int dstbase = tile * 16;
  if (dstbase >= NTGT) return;            // no barriers anywhere
  int ct0 = half * 4;

  f32x4 acc[4];
#pragma unroll
  for (int ct = 0; ct < 4; ++ct) acc[ct] = (f32x4){0.f, 0.f, 0.f, 0.f};

  // per-lane A-row base: row m of the tile; granule (ks*4+quad)*8 ushorts
  const ushort* a0 = mean + (size_t)(dstbase + m) * CH + (quad << 3);
  const ushort* at = xtb + (size_t)(dstbase + m) * CH + (quad << 3);

  bf16x8 aF[4], aN[4];
#pragma unroll
  for (int ks = 0; ks < 4; ++ks)
    aF[ks] = *(const bf16x8*)(a0 + ks * 32);

#pragma unroll
  for (int ph = 0; ph < NREL; ++ph) {
    // prefetch next phase's A-fragments (independent loads, no fences)
#pragma unroll
    for (int ks = 0; ks < 4; ++ks) {
      const ushort* an = (ph + 1 < NREL)
          ? (a0 + (size_t)(ph + 1) * NTGT * CH + ks * 32)
          : (at + ks * 32);
      aN[ks] = *(const bf16x8*)an;
    }
    const ushort* W = wb + (size_t)ph * CH * CH;
#pragma unroll
    for (int ct = 0; ct < 4; ++ct) {
      int n = (ct0 + ct) * 16 + m;
#pragma unroll
      for (int ks = 0; ks < 4; ++ks) {
        bf16x8 bF = *(const bf16x8*)(W + (size_t)n * CH + ks * 32 + quad * 8);
        acc[ct] = __builtin_amdgcn_mfma_f32_16x16x32_bf16(aF[ks], bF, acc[ct], 0, 0, 0);
      }
    }
#pragma unroll
    for (int ks = 0; ks < 4; ++ks) aF[ks] = aN[ks];
  }

  // ---- root: 4 register-masked phases (aF now holds the xtb tile frags) ----
  int myt = ntyp[dstbase + m];            // A-fragment row type (per lane)
#pragma unroll
  for (int ty = 0; ty < NTYP; ++ty) {
    union { uint u[4]; bf16x8 v; } aM[4];
#pragma unroll
    for (int ks = 0; ks < 4; ++ks) {
      union { bf16x8 v; uint u[4]; } sU; sU.v = aF[ks];
#pragma unroll
      for (int k2 = 0; k2 < 4; ++k2)
        aM[ks].u[k2] = (myt == ty) ? sU.u[k2] : 0u;
    }
    const ushort* W = wb + (size_t)(NREL + ty) * CH * CH;
#pragma unroll
    for (int ct = 0; ct < 4; ++ct) {
      int n = (ct0 + ct) * 16 + m;
#pragma unroll
      for (int ks = 0; ks < 4; ++ks) {
        bf16x8 bF = *(const bf16x8*)(W + (size_t)n * CH + ks * 32 + quad * 8);
        acc[ct] = __builtin_amdgcn_mfma_f32_16x16x32_bf16(aM[ks].v, bF, acc[ct], 0, 0, 0);
      }
    }
  }

  // ---- epilogue: add bias, plain coalesced store (64 cols per wave) ----
#pragma unroll
  for (int reg = 0; reg < 4; ++reg) {
    int row = quad * 4 + reg;
    int dst = dstbase + row;
    int tt = ntyp[dst];
    const float* rb = rootb + (size_t)tt * CH;
#pragma unroll
    for (int ct = 0; ct < 4; ++ct) {
      int col = (ct0 + ct) * 16 + m;
      out[(size_t)dst * CH + col] = acc[ct][reg] + rb[col];
    }
  }
}

extern "C" void kernel_launch(void* const* d_in, const int* in_sizes, int n_in,
                              void* d_out, int out_size, void* d_ws, size_t ws_size,
                              hipStream_t stream) {
  (void)in_sizes; (void)n_in; (void)out_size; (void)ws_size;
  const float* xsrc  = (const float*)d_in[0];
  const float* xt    = (const float*)d_in[1];
  const float* relw  = (const float*)d_in[2];
  const float* rootw = (const float*)d_in[3];
  const float* rootb = (const float*)d_in[4];
  const int* esrc = (const int*)d_in[5];
  const int* edst = (const int*)d_in[6];
  const int* etyp = (const int*)d_in[7];
  const int* ntyp = (const int*)d_in[8];
  float* out = (float*)d_out;

  char* ws = (char*)d_ws;
  int*   cnt    = (int*)(ws + CNT_O);
  int*   bsE    = (int*)(ws + BSE_O);
  int*   eoff   = (int*)(ws + EOFF_O);
  int*   cur    = (int*)(ws + CUR_O);
  int*   sedge  = (int*)(ws + SEDGE_O);
  ushort* wb    = (ushort*)(ws + WB_O);
  ushort* xb    = (ushort*)(ws + XB_O);
  ushort* xtb   = (ushort*)(ws + XTB_O);
  ushort* mean  = (ushort*)(ws + MEAN_O);

  hipMemsetAsync(cnt, 0, (size_t)NP * 4, stream);
  k_pre<<<dim3(CONVB + COUNTB), dim3(256), 0, stream>>>(
      xsrc, xt, relw, rootw, xb, xtb, wb, edst, etyp, cnt);
  k_s1<<<dim3(NB), dim3(256), 0, stream>>>(cnt, bsE);
  k_s23<<<dim3(NB), dim3(512), 0, stream>>>(cnt, bsE, eoff, cur);
  k_esort<<<dim3(COUNTB), dim3(256), 0, stream>>>(esrc, edst, etyp, cur, sedge);
  k_agg<<<dim3(AGGB), dim3(256), 0, stream>>>(xb, sedge, eoff, mean);
  k_gemm<<<dim3(GEMB), dim3(256), 0, stream>>>(
      mean, xtb, wb, ntyp, rootb, out);
}